// Round 9
// baseline (131.477 us; speedup 1.0000x reference)
//
#include <hip/hip_runtime.h>
#include <math.h>

#define N_ROWS 512
#define M_LEN  4096
#define D_DIM  8
#define NCHUNK 64        // af n-split: 1024 blocks, 8 n per chunk

__device__ __forceinline__ float2 f2(float x, float y) { return make_float2(x, y); }
__device__ __forceinline__ float2 cmul(float2 a, float2 b){
  return f2(a.x*b.x - a.y*b.y, a.x*b.y + a.y*b.x);
}
__device__ __forceinline__ float2 cadd(float2 a, float2 b){ return f2(a.x+b.x, a.y+b.y); }
__device__ __forceinline__ float2 csub(float2 a, float2 b){ return f2(a.x-b.x, a.y-b.y); }
__device__ __forceinline__ int ph(int i){ return i + (i>>4) + (i>>8); }
__device__ __forceinline__ int dr6(int j){
  int r = 0;
  #pragma unroll
  for (int i = 0; i < 6; ++i){ r = (r<<2) | (j & 3); j >>= 2; }
  return r;
}
// sin/cos of x REVOLUTIONS (hardware v_sin_f32/v_cos_f32, valid |x|<=256)
__device__ __forceinline__ float sin_rev(float x){ return __builtin_amdgcn_sinf(x); }
__device__ __forceinline__ float cos_rev(float x){ return __builtin_amdgcn_cosf(x); }

// ---------------------------------------------------------------------------
// prep: blocks 0..511   -> radix-4 DIT FFT of row b (round-8 proven body)
//       block  512      -> softmax of C_tilde rows (d-major store, proven math)
//       block  513      -> softmax of S_tilde rows (proven)
//       blocks 514..545 -> zero AF (256 KB)
// All __syncthreads are uniform within each block's branch.
// ---------------------------------------------------------------------------
__global__ __launch_bounds__(256) void prep_kernel(
    const float* __restrict__ X, const float* __restrict__ Ct,
    const float* __restrict__ St, float2* __restrict__ XF,
    float* __restrict__ C, float* __restrict__ S, float4* __restrict__ AF4) {
  __shared__ float2 buf[4368];             // ph(4095)=4365, 34.9 KB
  int b = blockIdx.x, tid = threadIdx.x;
  if (b < N_ROWS) {
    const float* x = X + (size_t)b * M_LEN;
    for (int j = tid; j < M_LEN; j += 256)
      buf[ph(dr6(j))] = f2(x[j], 0.0f);
    __syncthreads();
    for (int s = 0; s < 6; ++s) {
      int quarter = 1 << (2*s);
      float negInv = -1.0f / (float)(quarter << 2);   // revolutions per k
      for (int bi = tid; bi < 1024; bi += 256) {
        int k  = bi & (quarter - 1);
        int g  = bi >> (2*s);
        int i0 = (g << (2*s + 2)) + k;
        float rev = negInv * (float)k;
        float sw = sin_rev(rev), cw = cos_rev(rev);
        float2 w1 = f2(cw, sw);
        float2 w2 = cmul(w1, w1);
        float2 w3 = cmul(w2, w1);
        float2 a0 = buf[ph(i0)];
        float2 a1 = cmul(buf[ph(i0 +   quarter)], w1);
        float2 a2 = cmul(buf[ph(i0 + 2*quarter)], w2);
        float2 a3 = cmul(buf[ph(i0 + 3*quarter)], w3);
        float2 t0 = cadd(a0, a2), t1 = csub(a0, a2);
        float2 t2 = cadd(a1, a3), t3 = csub(a1, a3);
        buf[ph(i0)]             = cadd(t0, t2);
        buf[ph(i0 +   quarter)] = f2(t1.x + t3.y, t1.y - t3.x);  // t1 - i*t3
        buf[ph(i0 + 2*quarter)] = csub(t0, t2);
        buf[ph(i0 + 3*quarter)] = f2(t1.x - t3.y, t1.y + t3.x);  // t1 + i*t3
      }
      __syncthreads();
    }
    for (int j = tid; j < M_LEN; j += 256)
      XF[(size_t)b * M_LEN + j] = buf[ph(j)];
  } else if (b == N_ROWS) {
    // C softmax: 8 rows, one at a time (proven reduce pattern; d-major store)
    float* red = (float*)buf;
    for (int d = 0; d < D_DIM; ++d) {
      const float* row = Ct + d * N_ROWS;
      float v0 = row[tid], v1 = row[tid + 256];
      red[tid] = fmaxf(v0, v1); __syncthreads();
      for (int s = 128; s > 0; s >>= 1) {
        if (tid < s) red[tid] = fmaxf(red[tid], red[tid + s]);
        __syncthreads();
      }
      float m = red[0]; __syncthreads();
      float e0 = __expf(v0 - m), e1 = __expf(v1 - m);
      red[tid] = e0 + e1; __syncthreads();
      for (int s = 128; s > 0; s >>= 1) {
        if (tid < s) red[tid] += red[tid + s];
        __syncthreads();
      }
      float inv = 1.0f / red[0];
      __syncthreads();                     // protect red[0] before next d
      C[d * N_ROWS + tid]       = e0 * inv;
      C[d * N_ROWS + tid + 256] = e1 * inv;
    }
  } else if (b == N_ROWS + 1) {
    for (int n = tid; n < N_ROWS; n += 256) {
      float v[D_DIM]; float mx = -3.0e38f;
      #pragma unroll
      for (int d = 0; d < D_DIM; ++d) { v[d] = St[n * D_DIM + d]; mx = fmaxf(mx, v[d]); }
      float sum = 0.f;
      #pragma unroll
      for (int d = 0; d < D_DIM; ++d) { v[d] = __expf(v[d] - mx); sum += v[d]; }
      float inv = 1.0f / sum;
      #pragma unroll
      for (int d = 0; d < D_DIM; ++d) S[n * D_DIM + d] = v[d] * inv;
    }
  } else {
    // zero AF: 32 blocks x 256 threads x 2 float4 = 16384 float4 = 256 KB
    int i = (b - (N_ROWS + 2)) * 256 + tid;        // 0..8191
    float4 z = make_float4(0.f, 0.f, 0.f, 0.f);
    AF4[i] = z;
    AF4[i + 8192] = z;
  }
}

// ---------------------------------------------------------------------------
// af (round-8 structure, proven; NCHUNK 32->64): one thread per m, all 8 d
// accumulators in registers; XF loaded once; atomicAdd into AF[d][m].
// grid = NCHUNK*16 = 1024 blocks.
// ---------------------------------------------------------------------------
__global__ __launch_bounds__(256) void af_kernel(
    const float2* __restrict__ XF, const float* __restrict__ C,
    const float* __restrict__ tau, float* __restrict__ AF) {
  int bid   = blockIdx.x;
  int chunk = bid >> 4;                            // 0..NCHUNK-1
  int m     = (bid & 15) * 256 + threadIdx.x;      // 0..4095
  float fm  = (float)m * (1.0f / (float)M_LEN);
  float accr[D_DIM], acci[D_DIM];
  #pragma unroll
  for (int d = 0; d < D_DIM; ++d) { accr[d] = 0.f; acci[d] = 0.f; }
  int n0 = chunk * (N_ROWS / NCHUNK);
  #pragma unroll
  for (int nn = 0; nn < N_ROWS / NCHUNK; ++nn) {
    int n = n0 + nn;
    float2 Xv = XF[(size_t)n * M_LEN + m];
    #pragma unroll
    for (int d = 0; d < D_DIM; ++d) {
      float t = tau[n * D_DIM + d];                // wave-uniform
      float c = C[d * N_ROWS + n];                 // wave-uniform
      float r = t * fm;                            // revolutions
      float s_ = sin_rev(r), c_ = cos_rev(r);
      // conj(omega) = (c_, +s_)
      accr[d] += c * (Xv.x * c_ - Xv.y * s_);
      acci[d] += c * (Xv.x * s_ + Xv.y * c_);
    }
  }
  #pragma unroll
  for (int d = 0; d < D_DIM; ++d) {
    atomicAdd(&AF[2 * ((d << 12) + m)],     accr[d]);
    atomicAdd(&AF[2 * ((d << 12) + m) + 1], acci[d]);
  }
}

// ---------------------------------------------------------------------------
// out (round-8 verbatim, proven)
// ---------------------------------------------------------------------------
__global__ __launch_bounds__(256) void out_kernel(
    const float2* __restrict__ AF, const float* __restrict__ S,
    const float* __restrict__ tau, float* __restrict__ out, int interleaved) {
  int idx = blockIdx.x * 256 + threadIdx.x;   // over N*M
  int n = idx >> 12;
  int m = idx & (M_LEN - 1);
  float fm = (float)m * (1.0f / (float)M_LEN);
  float xr = 0.f, xi = 0.f;
  #pragma unroll
  for (int d = 0; d < D_DIM; ++d) {
    float s = S[n * D_DIM + d];                 // wave-uniform
    float t = tau[n * D_DIM + d];               // wave-uniform
    float r = t * fm;                           // revolutions
    float sa = sin_rev(r), ca = cos_rev(r);
    float2 A = AF[(d << 12) + m];
    // omega = (ca, -sa); omega*A = (ca*Ax + sa*Ay, ca*Ay - sa*Ax)
    xr += s * (ca * A.x + sa * A.y);
    xi += s * (ca * A.y - sa * A.x);
  }
  if (interleaved) {
    ((float2*)out)[idx] = f2(xr, xi);
  } else {
    out[idx] = xr;
  }
}

extern "C" void kernel_launch(void* const* d_in, const int* in_sizes, int n_in,
                              void* d_out, int out_size, void* d_ws, size_t ws_size,
                              hipStream_t stream) {
  const float* X  = (const float*)d_in[0];   // [512, 4096]
  const float* Ct = (const float*)d_in[1];   // [8, 512]
  const float* St = (const float*)d_in[2];   // [512, 8]
  const float* tau= (const float*)d_in[3];   // [512, 8]

  // workspace layout identical to rounds 1/5/6/7/8 (passed 5x)
  char* ws = (char*)d_ws;
  const size_t XF_BYTES = (size_t)N_ROWS * M_LEN * sizeof(float2);   // 16 MB
  const size_t AF_BYTES = (size_t)D_DIM * M_LEN * sizeof(float2);    // 256 KB
  const size_t C_BYTES  = (size_t)D_DIM * N_ROWS * sizeof(float);    // 16 KB
  float2* XF = (float2*)ws;
  float2* AF = (float2*)(ws + XF_BYTES);
  float*  C  = (float*)(ws + XF_BYTES + AF_BYTES);
  float*  S  = (float*)(ws + XF_BYTES + AF_BYTES + C_BYTES);

  int interleaved = (out_size >= 2 * N_ROWS * M_LEN) ? 1 : 0;

  prep_kernel<<<N_ROWS + 2 + 32, 256, 0, stream>>>(X, Ct, St, XF, C, S, (float4*)AF);
  af_kernel<<<NCHUNK * 16, 256, 0, stream>>>(XF, C, tau, (float*)AF);
  out_kernel<<<(N_ROWS * M_LEN) / 256, 256, 0, stream>>>(AF, S, tau, (float*)d_out, interleaved);
}

// Round 10
// 115.036 us; speedup vs baseline: 1.1429x; 1.1429x over previous
//
#include <hip/hip_runtime.h>
#include <math.h>

#define N_ROWS 512
#define M_LEN  4096
#define D_DIM  8
#define NCHUNK 8

__device__ __forceinline__ float2 f2(float x, float y) { return make_float2(x, y); }
__device__ __forceinline__ float2 cmul(float2 a, float2 b){
  return f2(a.x*b.x - a.y*b.y, a.x*b.y + a.y*b.x);
}
__device__ __forceinline__ float2 cadd(float2 a, float2 b){ return f2(a.x+b.x, a.y+b.y); }
__device__ __forceinline__ float2 csub(float2 a, float2 b){ return f2(a.x-b.x, a.y-b.y); }
__device__ __forceinline__ int ph(int i){ return i + (i>>4) + (i>>8); }
__device__ __forceinline__ int dr6(int j){
  int r = 0;
  #pragma unroll
  for (int i = 0; i < 6; ++i){ r = (r<<2) | (j & 3); j >>= 2; }
  return r;
}
// sin/cos of x REVOLUTIONS (hardware v_sin_f32/v_cos_f32, valid |x|<=256)
__device__ __forceinline__ float sin_rev(float x){ return __builtin_amdgcn_sinf(x); }
__device__ __forceinline__ float cos_rev(float x){ return __builtin_amdgcn_cosf(x); }

static constexpr float TWO_PI = 6.283185307179586476925f;

// ---------------------------------------------------------------------------
// Softmaxes (round-1 verbatim, proven 5x)
// ---------------------------------------------------------------------------
__global__ __launch_bounds__(256) void softmax_kernel(
    const float* __restrict__ Ct, const float* __restrict__ St,
    float* __restrict__ C, float* __restrict__ S) {
  int b = blockIdx.x, tid = threadIdx.x;
  if (b < D_DIM) {
    __shared__ float red[256];
    const float* row = Ct + b * N_ROWS;
    float v0 = row[tid], v1 = row[tid + 256];
    float mx = fmaxf(v0, v1);
    red[tid] = mx; __syncthreads();
    for (int s = 128; s > 0; s >>= 1) {
      if (tid < s) red[tid] = fmaxf(red[tid], red[tid + s]);
      __syncthreads();
    }
    float m = red[0];
    __syncthreads();
    float e0 = __expf(v0 - m), e1 = __expf(v1 - m);
    red[tid] = e0 + e1; __syncthreads();
    for (int s = 128; s > 0; s >>= 1) {
      if (tid < s) red[tid] += red[tid + s];
      __syncthreads();
    }
    float inv = 1.0f / red[0];
    C[b * N_ROWS + tid]       = e0 * inv;
    C[b * N_ROWS + tid + 256] = e1 * inv;
  } else {
    int n = (b - D_DIM) * 256 + tid;
    if (n < N_ROWS) {
      float v[D_DIM];
      float mx = -3.0e38f;
      #pragma unroll
      for (int d = 0; d < D_DIM; ++d) { v[d] = St[n * D_DIM + d]; mx = fmaxf(mx, v[d]); }
      float sum = 0.f;
      #pragma unroll
      for (int d = 0; d < D_DIM; ++d) { v[d] = __expf(v[d] - mx); sum += v[d]; }
      float inv = 1.0f / sum;
      #pragma unroll
      for (int d = 0; d < D_DIM; ++d) S[n * D_DIM + d] = v[d] * inv;
    }
  }
}

// ---------------------------------------------------------------------------
// Radix-4 DIT FFT (round-7 champion structure; twiddles now v_sin/v_cos)
//   X_F[k] = sum_j x[j] exp(-2*pi*i*j*k/M)
// ---------------------------------------------------------------------------
__global__ __launch_bounds__(256) void fft_kernel(
    const float* __restrict__ X, float2* __restrict__ XF) {
  __shared__ float2 buf[4368];             // ph(4095)=4365, 34.9 KB
  int row = blockIdx.x;
  int tid = threadIdx.x;
  const float* x = X + (size_t)row * M_LEN;
  for (int j = tid; j < M_LEN; j += 256)
    buf[ph(dr6(j))] = f2(x[j], 0.0f);
  __syncthreads();
  for (int s = 0; s < 6; ++s) {
    int quarter = 1 << (2*s);
    float negInv = -1.0f / (float)(quarter << 2);   // revolutions per k
    for (int bi = tid; bi < 1024; bi += 256) {
      int k  = bi & (quarter - 1);
      int g  = bi >> (2*s);
      int i0 = (g << (2*s + 2)) + k;
      float rev = negInv * (float)k;                // in (-0.25, 0]
      float sw = sin_rev(rev), cw = cos_rev(rev);
      float2 w1 = f2(cw, sw);
      float2 w2 = cmul(w1, w1);
      float2 w3 = cmul(w2, w1);
      float2 a0 = buf[ph(i0)];
      float2 a1 = cmul(buf[ph(i0 +   quarter)], w1);
      float2 a2 = cmul(buf[ph(i0 + 2*quarter)], w2);
      float2 a3 = cmul(buf[ph(i0 + 3*quarter)], w3);
      float2 t0 = cadd(a0, a2), t1 = csub(a0, a2);
      float2 t2 = cadd(a1, a3), t3 = csub(a1, a3);
      buf[ph(i0)]             = cadd(t0, t2);
      buf[ph(i0 +   quarter)] = f2(t1.x + t3.y, t1.y - t3.x);  // t1 - i*t3
      buf[ph(i0 + 2*quarter)] = csub(t0, t2);
      buf[ph(i0 + 3*quarter)] = f2(t1.x - t3.y, t1.y + t3.x);  // t1 + i*t3
    }
    __syncthreads();
  }
  for (int j = tid; j < M_LEN; j += 256)
    XF[(size_t)row * M_LEN + j] = buf[ph(j)];
}

// ---------------------------------------------------------------------------
// zero AF (ws is poisoned to 0xAA before every launch)
// ---------------------------------------------------------------------------
__global__ __launch_bounds__(256) void zero_af_kernel(float4* __restrict__ AF) {
  int i = blockIdx.x * 256 + threadIdx.x;          // 16384 float4 = 256 KB
  if (i < (D_DIM * M_LEN) / 2)
    AF[i] = make_float4(0.f, 0.f, 0.f, 0.f);
}

// ---------------------------------------------------------------------------
// af (round-6/7 champion structure: d-in-lane, NCHUNK=8 -> only 524K atomics;
// XF 8x re-read rides L2/L3 which measurement shows is cheaper than atomic
// contention). Phases now v_sin/v_cos.
// ---------------------------------------------------------------------------
__global__ __launch_bounds__(256) void af_kernel(
    const float2* __restrict__ XF, const float* __restrict__ C,
    const float* __restrict__ tau, float* __restrict__ AF) {
  int bid   = blockIdx.x;
  int chunk = bid >> 7;                            // 0..NCHUNK-1
  int idx   = (bid & 127) * 256 + threadIdx.x;     // 0..32767 over d*M
  int d = idx >> 12;
  int m = idx & (M_LEN - 1);
  float fm = (float)m * (1.0f / (float)M_LEN);
  float accr = 0.f, acci = 0.f;
  int n0 = chunk * (N_ROWS / NCHUNK);
  #pragma unroll 8
  for (int nn = 0; nn < N_ROWS / NCHUNK; ++nn) {
    int n = n0 + nn;
    float c = C[d * N_ROWS + n];                   // block-uniform
    float t = tau[n * D_DIM + d];                  // block-uniform
    float r = t * fm;                              // revolutions
    float sa = sin_rev(r), ca = cos_rev(r);
    float2 Xv = XF[(size_t)n * M_LEN + m];
    // conj(omega) = (ca, +sa)
    accr += c * (Xv.x * ca - Xv.y * sa);
    acci += c * (Xv.x * sa + Xv.y * ca);
  }
  if (idx < D_DIM * M_LEN) {
    atomicAdd(&AF[2 * idx],     accr);
    atomicAdd(&AF[2 * idx + 1], acci);
  }
}

// ---------------------------------------------------------------------------
// out (round-1 structure, proven 5x; phases now v_sin/v_cos)
// ---------------------------------------------------------------------------
__global__ __launch_bounds__(256) void out_kernel(
    const float2* __restrict__ AF, const float* __restrict__ S,
    const float* __restrict__ tau, float* __restrict__ out, int interleaved) {
  int idx = blockIdx.x * 256 + threadIdx.x;   // over N*M
  int n = idx >> 12;
  int m = idx & (M_LEN - 1);
  float fm = (float)m * (1.0f / (float)M_LEN);
  float xr = 0.f, xi = 0.f;
  #pragma unroll
  for (int d = 0; d < D_DIM; ++d) {
    float s = S[n * D_DIM + d];                 // block-uniform
    float t = tau[n * D_DIM + d];               // block-uniform
    float r = t * fm;                           // revolutions
    float sa = sin_rev(r), ca = cos_rev(r);
    float2 A = AF[(d << 12) + m];
    // omega = (ca, -sa); omega*A = (ca*Ax + sa*Ay, ca*Ay - sa*Ax)
    xr += s * (ca * A.x + sa * A.y);
    xi += s * (ca * A.y - sa * A.x);
  }
  if (interleaved) {
    ((float2*)out)[idx] = f2(xr, xi);
  } else {
    out[idx] = xr;
  }
}

extern "C" void kernel_launch(void* const* d_in, const int* in_sizes, int n_in,
                              void* d_out, int out_size, void* d_ws, size_t ws_size,
                              hipStream_t stream) {
  const float* X  = (const float*)d_in[0];   // [512, 4096]
  const float* Ct = (const float*)d_in[1];   // [8, 512]
  const float* St = (const float*)d_in[2];   // [512, 8]
  const float* tau= (const float*)d_in[3];   // [512, 8]

  // workspace layout identical to all passing rounds
  char* ws = (char*)d_ws;
  const size_t XF_BYTES = (size_t)N_ROWS * M_LEN * sizeof(float2);   // 16 MB
  const size_t AF_BYTES = (size_t)D_DIM * M_LEN * sizeof(float2);    // 256 KB
  const size_t C_BYTES  = (size_t)D_DIM * N_ROWS * sizeof(float);    // 16 KB
  float2* XF = (float2*)ws;
  float2* AF = (float2*)(ws + XF_BYTES);
  float*  C  = (float*)(ws + XF_BYTES + AF_BYTES);
  float*  S  = (float*)(ws + XF_BYTES + AF_BYTES + C_BYTES);

  int interleaved = (out_size >= 2 * N_ROWS * M_LEN) ? 1 : 0;

  softmax_kernel<<<D_DIM + (N_ROWS + 255) / 256, 256, 0, stream>>>(Ct, St, C, S);
  fft_kernel<<<N_ROWS, 256, 0, stream>>>(X, XF);
  zero_af_kernel<<<(D_DIM * M_LEN / 2 + 255) / 256, 256, 0, stream>>>((float4*)AF);
  af_kernel<<<NCHUNK * 128, 256, 0, stream>>>(XF, C, tau, (float*)AF);
  out_kernel<<<(N_ROWS * M_LEN) / 256, 256, 0, stream>>>(AF, S, tau, (float*)d_out, interleaved);
}

// Round 12
// 111.065 us; speedup vs baseline: 1.1838x; 1.0357x over previous
//
#include <hip/hip_runtime.h>
#include <math.h>

#define N_ROWS 512
#define M_LEN  4096
#define D_DIM  8
#define NCHUNK 8

__device__ __forceinline__ float2 f2(float x, float y) { return make_float2(x, y); }
__device__ __forceinline__ float2 cmul(float2 a, float2 b){
  return f2(a.x*b.x - a.y*b.y, a.x*b.y + a.y*b.x);
}
__device__ __forceinline__ float2 cadd(float2 a, float2 b){ return f2(a.x+b.x, a.y+b.y); }
__device__ __forceinline__ float2 csub(float2 a, float2 b){ return f2(a.x-b.x, a.y-b.y); }
__device__ __forceinline__ int ph(int i){ return i + (i>>4) + (i>>8); }
__device__ __forceinline__ int dr6(int j){
  int r = 0;
  #pragma unroll
  for (int i = 0; i < 6; ++i){ r = (r<<2) | (j & 3); j >>= 2; }
  return r;
}
// sin/cos of x REVOLUTIONS (hardware v_sin_f32/v_cos_f32, valid |x|<=256)
__device__ __forceinline__ float sin_rev(float x){ return __builtin_amdgcn_sinf(x); }
__device__ __forceinline__ float cos_rev(float x){ return __builtin_amdgcn_cosf(x); }

// ---------------------------------------------------------------------------
// prep (round-9 verbatim, proven): blocks 0..511 -> radix-4 FFT of row b
//   block 512 -> C softmax (d-major store); block 513 -> S softmax;
//   blocks 514..545 -> zero AF. All __syncthreads uniform per branch.
// ---------------------------------------------------------------------------
__global__ __launch_bounds__(256) void prep_kernel(
    const float* __restrict__ X, const float* __restrict__ Ct,
    const float* __restrict__ St, float2* __restrict__ XF,
    float* __restrict__ C, float* __restrict__ S, float4* __restrict__ AF4) {
  __shared__ float2 buf[4368];             // ph(4095)=4365, 34.9 KB
  int b = blockIdx.x, tid = threadIdx.x;
  if (b < N_ROWS) {
    const float* x = X + (size_t)b * M_LEN;
    for (int j = tid; j < M_LEN; j += 256)
      buf[ph(dr6(j))] = f2(x[j], 0.0f);
    __syncthreads();
    for (int s = 0; s < 6; ++s) {
      int quarter = 1 << (2*s);
      float negInv = -1.0f / (float)(quarter << 2);   // revolutions per k
      for (int bi = tid; bi < 1024; bi += 256) {
        int k  = bi & (quarter - 1);
        int g  = bi >> (2*s);
        int i0 = (g << (2*s + 2)) + k;
        float rev = negInv * (float)k;
        float sw = sin_rev(rev), cw = cos_rev(rev);
        float2 w1 = f2(cw, sw);
        float2 w2 = cmul(w1, w1);
        float2 w3 = cmul(w2, w1);
        float2 a0 = buf[ph(i0)];
        float2 a1 = cmul(buf[ph(i0 +   quarter)], w1);
        float2 a2 = cmul(buf[ph(i0 + 2*quarter)], w2);
        float2 a3 = cmul(buf[ph(i0 + 3*quarter)], w3);
        float2 t0 = cadd(a0, a2), t1 = csub(a0, a2);
        float2 t2 = cadd(a1, a3), t3 = csub(a1, a3);
        buf[ph(i0)]             = cadd(t0, t2);
        buf[ph(i0 +   quarter)] = f2(t1.x + t3.y, t1.y - t3.x);  // t1 - i*t3
        buf[ph(i0 + 2*quarter)] = csub(t0, t2);
        buf[ph(i0 + 3*quarter)] = f2(t1.x - t3.y, t1.y + t3.x);  // t1 + i*t3
      }
      __syncthreads();
    }
    for (int j = tid; j < M_LEN; j += 256)
      XF[(size_t)b * M_LEN + j] = buf[ph(j)];
  } else if (b == N_ROWS) {
    // C softmax: 8 rows sequentially (proven reduce pattern; d-major store)
    float* red = (float*)buf;
    for (int d = 0; d < D_DIM; ++d) {
      const float* row = Ct + d * N_ROWS;
      float v0 = row[tid], v1 = row[tid + 256];
      red[tid] = fmaxf(v0, v1); __syncthreads();
      for (int s = 128; s > 0; s >>= 1) {
        if (tid < s) red[tid] = fmaxf(red[tid], red[tid + s]);
        __syncthreads();
      }
      float m = red[0]; __syncthreads();
      float e0 = __expf(v0 - m), e1 = __expf(v1 - m);
      red[tid] = e0 + e1; __syncthreads();
      for (int s = 128; s > 0; s >>= 1) {
        if (tid < s) red[tid] += red[tid + s];
        __syncthreads();
      }
      float inv = 1.0f / red[0];
      __syncthreads();                     // protect red[0] before next d
      C[d * N_ROWS + tid]       = e0 * inv;
      C[d * N_ROWS + tid + 256] = e1 * inv;
    }
  } else if (b == N_ROWS + 1) {
    for (int n = tid; n < N_ROWS; n += 256) {
      float v[D_DIM]; float mx = -3.0e38f;
      #pragma unroll
      for (int d = 0; d < D_DIM; ++d) { v[d] = St[n * D_DIM + d]; mx = fmaxf(mx, v[d]); }
      float sum = 0.f;
      #pragma unroll
      for (int d = 0; d < D_DIM; ++d) { v[d] = __expf(v[d] - mx); sum += v[d]; }
      float inv = 1.0f / sum;
      #pragma unroll
      for (int d = 0; d < D_DIM; ++d) S[n * D_DIM + d] = v[d] * inv;
    }
  } else {
    // zero AF: 32 blocks x 256 threads x 2 float4 = 16384 float4 = 256 KB
    int i = (b - (N_ROWS + 2)) * 256 + tid;        // 0..8191
    float4 z = make_float4(0.f, 0.f, 0.f, 0.f);
    AF4[i] = z;
    AF4[i + 8192] = z;
  }
}

// ---------------------------------------------------------------------------
// af (round-10 champion verbatim: d block-uniform, NCHUNK=8 -> 524K atomics;
// XF 8x re-read rides L2/L3 which measurement shows is cheaper than atomics)
// ---------------------------------------------------------------------------
__global__ __launch_bounds__(256) void af_kernel(
    const float2* __restrict__ XF, const float* __restrict__ C,
    const float* __restrict__ tau, float* __restrict__ AF) {
  int bid   = blockIdx.x;
  int chunk = bid >> 7;                            // 0..NCHUNK-1
  int idx   = (bid & 127) * 256 + threadIdx.x;     // 0..32767 over d*M
  int d = idx >> 12;
  int m = idx & (M_LEN - 1);
  float fm = (float)m * (1.0f / (float)M_LEN);
  float accr = 0.f, acci = 0.f;
  int n0 = chunk * (N_ROWS / NCHUNK);
  #pragma unroll 8
  for (int nn = 0; nn < N_ROWS / NCHUNK; ++nn) {
    int n = n0 + nn;
    float c = C[d * N_ROWS + n];                   // block-uniform
    float t = tau[n * D_DIM + d];                  // block-uniform
    float r = t * fm;                              // revolutions
    float sa = sin_rev(r), ca = cos_rev(r);
    float2 Xv = XF[(size_t)n * M_LEN + m];
    // conj(omega) = (ca, +sa)
    accr += c * (Xv.x * ca - Xv.y * sa);
    acci += c * (Xv.x * sa + Xv.y * ca);
  }
  if (idx < D_DIM * M_LEN) {
    atomicAdd(&AF[2 * idx],     accr);
    atomicAdd(&AF[2 * idx + 1], acci);
  }
}

// ---------------------------------------------------------------------------
// out (round-10 verbatim, proven)
// ---------------------------------------------------------------------------
__global__ __launch_bounds__(256) void out_kernel(
    const float2* __restrict__ AF, const float* __restrict__ S,
    const float* __restrict__ tau, float* __restrict__ out, int interleaved) {
  int idx = blockIdx.x * 256 + threadIdx.x;   // over N*M
  int n = idx >> 12;
  int m = idx & (M_LEN - 1);
  float fm = (float)m * (1.0f / (float)M_LEN);
  float xr = 0.f, xi = 0.f;
  #pragma unroll
  for (int d = 0; d < D_DIM; ++d) {
    float s = S[n * D_DIM + d];                 // block-uniform
    float t = tau[n * D_DIM + d];               // block-uniform
    float r = t * fm;                           // revolutions
    float sa = sin_rev(r), ca = cos_rev(r);
    float2 A = AF[(d << 12) + m];
    // omega = (ca, -sa); omega*A = (ca*Ax + sa*Ay, ca*Ay - sa*Ax)
    xr += s * (ca * A.x + sa * A.y);
    xi += s * (ca * A.y - sa * A.x);
  }
  if (interleaved) {
    ((float2*)out)[idx] = f2(xr, xi);
  } else {
    out[idx] = xr;
  }
}

extern "C" void kernel_launch(void* const* d_in, const int* in_sizes, int n_in,
                              void* d_out, int out_size, void* d_ws, size_t ws_size,
                              hipStream_t stream) {
  const float* X  = (const float*)d_in[0];   // [512, 4096]
  const float* Ct = (const float*)d_in[1];   // [8, 512]
  const float* St = (const float*)d_in[2];   // [512, 8]
  const float* tau= (const float*)d_in[3];   // [512, 8]

  // workspace layout identical to all passing rounds
  char* ws = (char*)d_ws;
  const size_t XF_BYTES = (size_t)N_ROWS * M_LEN * sizeof(float2);   // 16 MB
  const size_t AF_BYTES = (size_t)D_DIM * M_LEN * sizeof(float2);    // 256 KB
  const size_t C_BYTES  = (size_t)D_DIM * N_ROWS * sizeof(float);    // 16 KB
  float2* XF = (float2*)ws;
  float2* AF = (float2*)(ws + XF_BYTES);
  float*  C  = (float*)(ws + XF_BYTES + AF_BYTES);
  float*  S  = (float*)(ws + XF_BYTES + AF_BYTES + C_BYTES);

  int interleaved = (out_size >= 2 * N_ROWS * M_LEN) ? 1 : 0;

  prep_kernel<<<N_ROWS + 2 + 32, 256, 0, stream>>>(X, Ct, St, XF, C, S, (float4*)AF);
  af_kernel<<<NCHUNK * 128, 256, 0, stream>>>(XF, C, tau, (float*)AF);
  out_kernel<<<(N_ROWS * M_LEN) / 256, 256, 0, stream>>>(AF, S, tau, (float*)d_out, interleaved);
}